// Round 1
// baseline (12176.230 us; speedup 1.0000x reference)
//
#include <hip/hip_runtime.h>
#include <hip/hip_bf16.h>
#include <hip/hip_cooperative_groups.h>

namespace cg = cooperative_groups;

typedef unsigned short u16;
typedef __attribute__((ext_vector_type(8))) short short8;
typedef __attribute__((ext_vector_type(4))) float f32x4;

static constexpr int NB = 256;    // batch
static constexpr int NN = 2048;   // hidden n
static constexpr int KK = 2048;   // contraction dim
static constexpr int DD = 512;    // input features
static constexpr float ALPHA = 0.1f;
static constexpr float TOLF = 1e-4f;
static constexpr int MAXIT = 300;

__device__ __forceinline__ float bf2f(u16 u) {
  union { unsigned int i; float f; } v; v.i = ((unsigned int)u) << 16; return v.f;
}
__device__ __forceinline__ u16 f2bf(float f) {  // RNE bf16
  union { float f; unsigned int i; } v; v.f = f;
  unsigned int x = v.i;
  return (u16)((x + 0x7fffu + ((x >> 16) & 1u)) >> 16);
}

// ---------------- K1: Aht[i][k] = bf16(A[k][i]), Alt = residual ----------------
__global__ __launch_bounds__(256) void k_transpose_split(
    const float* __restrict__ A, u16* __restrict__ Aht, u16* __restrict__ Alt) {
  __shared__ float tile[64][65];
  int bx = blockIdx.x & 31;   // i-tile
  int by = blockIdx.x >> 5;   // k-tile
  int i0 = bx << 6, k0 = by << 6;
  int c = threadIdx.x & 63, r4 = threadIdx.x >> 6;
  for (int rr = r4; rr < 64; rr += 4)
    tile[rr][c] = A[(size_t)(k0 + rr) * NN + i0 + c];
  __syncthreads();
  for (int rr = r4; rr < 64; rr += 4) {
    float v = tile[c][rr];                       // = A[k0+c][i0+rr]
    size_t o = (size_t)(i0 + rr) * KK + k0 + c;  // Aht[i][k]
    u16 hv = f2bf(v);
    Aht[o] = hv;
    Alt[o] = f2bf(v - bf2f(hv));
  }
}

// ------ K2: T = (1 - a*m) I + a*(S - S^T - A^T A), stored row-major bf16 split ------
// G[i][j] = sum_k At[i][k]*At[j][k]; split GEMM: Gh*h + l*h + h*l
__global__ __launch_bounds__(512) void k_build_T(
    const u16* __restrict__ Aht, const u16* __restrict__ Alt,
    const float* __restrict__ S, const float* __restrict__ mraw,
    u16* __restrict__ Th, u16* __restrict__ Tl) {
  int bid = blockIdx.x;            // 256 blocks, output tile 128x128
  int it0 = (bid >> 4) << 7;
  int jt0 = (bid & 15) << 7;
  int lane = threadIdx.x & 63, wid = threadIdx.x >> 6;
  int wm = wid >> 2, wn = wid & 3; // 2x4 waves, wave tile 64x32
  int ib = it0 + wm * 64;
  int jb = jt0 + wn * 32;
  int lcol = lane & 15, kg = lane >> 4;
  f32x4 acc[4][2] = {};
  size_t ar[4], br[2];
#pragma unroll
  for (int mf = 0; mf < 4; ++mf) ar[mf] = (size_t)(ib + mf * 16 + lcol) * KK + kg * 8;
#pragma unroll
  for (int nf = 0; nf < 2; ++nf) br[nf] = (size_t)(jb + nf * 16 + lcol) * KK + kg * 8;
  for (int kk = 0; kk < KK; kk += 32) {
    short8 ah[4], al[4], bh[2], bl[2];
#pragma unroll
    for (int mf = 0; mf < 4; ++mf) {
      ah[mf] = *(const short8*)(Aht + ar[mf] + kk);
      al[mf] = *(const short8*)(Alt + ar[mf] + kk);
    }
#pragma unroll
    for (int nf = 0; nf < 2; ++nf) {
      bh[nf] = *(const short8*)(Aht + br[nf] + kk);
      bl[nf] = *(const short8*)(Alt + br[nf] + kk);
    }
#pragma unroll
    for (int mf = 0; mf < 4; ++mf)
#pragma unroll
      for (int nf = 0; nf < 2; ++nf) {
        acc[mf][nf] = __builtin_amdgcn_mfma_f32_16x16x32_bf16(ah[mf], bh[nf], acc[mf][nf], 0, 0, 0);
        acc[mf][nf] = __builtin_amdgcn_mfma_f32_16x16x32_bf16(al[mf], bh[nf], acc[mf][nf], 0, 0, 0);
        acc[mf][nf] = __builtin_amdgcn_mfma_f32_16x16x32_bf16(ah[mf], bl[nf], acc[mf][nf], 0, 0, 0);
      }
  }
  float m = log1pf(expf(mraw[0]));   // softplus
  float dg = 1.0f - ALPHA * m;
#pragma unroll
  for (int mf = 0; mf < 4; ++mf)
#pragma unroll
    for (int nf = 0; nf < 2; ++nf)
#pragma unroll
      for (int e = 0; e < 4; ++e) {
        int i = ib + mf * 16 + kg * 4 + e;   // D row = (lane>>4)*4+e  [m89-verified]
        int j = jb + nf * 16 + lcol;         // D col = lane&15
        float tv = ALPHA * (S[(size_t)i * NN + j] - S[(size_t)j * NN + i] - acc[mf][nf][e]);
        if (i == j) tv += dg;
        size_t o = (size_t)i * KK + j;
        u16 hv = f2bf(tv);
        Th[o] = hv;
        Tl[o] = f2bf(tv - bf2f(hv));
      }
}

// ---------------- K3: cp[b][n] = a*(U[n,:]·x[b,:] + bias[n]) ----------------
__global__ __launch_bounds__(256) void k_build_c(
    const float* __restrict__ U, const float* __restrict__ bias,
    const float* __restrict__ x, float* __restrict__ cp) {
  int b = blockIdx.x >> 3;
  int n = ((blockIdx.x & 7) << 8) + threadIdx.x;
  const float4* xr = (const float4*)(x + (size_t)b * DD);
  const float4* ur = (const float4*)(U + (size_t)n * DD);
  float acc = 0.f;
  for (int d = 0; d < DD / 4; ++d) {
    float4 xv = xr[d], uv = ur[d];
    acc += xv.x * uv.x + xv.y * uv.y + xv.z * uv.z + xv.w * uv.w;
  }
  cp[(size_t)b * NN + n] = ALPHA * (acc + bias[n]);
}

// ---------------- K4: cooperative fixed-point iteration ----------------
// y (=z^T, [b][n] fp32) ; yh/yl bf16 splits (A-operand) ; Th/Tl row-major (B-operand)
// y' = relu(y*T^T + cp). One grid.sync per iteration; ping-pong blockSums.
__global__ __launch_bounds__(512) void k_iterate(
    const u16* __restrict__ Th, const u16* __restrict__ Tl,
    const float* __restrict__ cp, float* __restrict__ y,
    u16* __restrict__ yh, u16* __restrict__ yl,
    float2* __restrict__ bsums, float* __restrict__ out) {
  cg::grid_group grid = cg::this_grid();
  int bid = blockIdx.x;
  // XCD swizzle: all 8 batch-tiles of an n-panel share one XCD's L2
  int xcd = bid & 7, g = bid >> 3;
  int ntile = xcd * 4 + (g & 3);   // 0..31
  int btile = g >> 2;              // 0..7
  int b0 = btile * 32, n0 = ntile * 64;
  int tid = threadIdx.x, lane = tid & 63, wid = tid >> 6;
  int wm = wid >> 2, wn = wid & 3;   // 2x4 waves of 16x16
  int lcol = lane & 15, kg = lane >> 4;
  int wb = b0 + wm * 16;
  int wn0 = n0 + wn * 16;
  size_t aoff = (size_t)(wb + lcol) * KK + kg * 8;   // into yh/yl
  size_t boff = (size_t)(wn0 + lcol) * KK + kg * 8;  // into Th/Tl
  int eb = wb + kg * 4;
  int en = wn0 + lcol;

  // zero own y tile (only this block ever touches it until the final write)
  for (int i = tid; i < 32 * 64; i += 512)
    y[(size_t)(b0 + (i >> 6)) * NN + n0 + (i & 63)] = 0.f;

  __shared__ float red0[8], red1[8];
  __shared__ int sflag;
  f32x4 a0 = {}, a1 = {}, a2 = {};

  for (int it = 0; it < MAXIT; ++it) {
    if (it > 0) {
#pragma unroll 4
      for (int kk = 0; kk < KK; kk += 32) {
        short8 avh = *(const short8*)(yh + aoff + kk);
        short8 avl = *(const short8*)(yl + aoff + kk);
        short8 bvh = *(const short8*)(Th + boff + kk);
        short8 bvl = *(const short8*)(Tl + boff + kk);
        a0 = __builtin_amdgcn_mfma_f32_16x16x32_bf16(avh, bvh, a0, 0, 0, 0);
        a1 = __builtin_amdgcn_mfma_f32_16x16x32_bf16(avl, bvh, a1, 0, 0, 0);
        a2 = __builtin_amdgcn_mfma_f32_16x16x32_bf16(avh, bvl, a2, 0, 0, 0);
      }
    }
    float dsq = 0.f, zsq = 0.f;
#pragma unroll
    for (int e = 0; e < 4; ++e) {
      size_t idx = (size_t)(eb + e) * NN + en;
      float p = a0[e] + a1[e] + a2[e] + cp[idx];
      float zn = fmaxf(p, 0.f);
      float zo = y[idx];
      float d = zn - zo;
      dsq += d * d;
      zsq += zo * zo;
      y[idx] = zn;
      u16 hv = f2bf(zn);
      yh[idx] = hv;
      yl[idx] = f2bf(zn - bf2f(hv));
    }
    a0 = (f32x4){0.f, 0.f, 0.f, 0.f};
    a1 = (f32x4){0.f, 0.f, 0.f, 0.f};
    a2 = (f32x4){0.f, 0.f, 0.f, 0.f};
#pragma unroll
    for (int o = 32; o > 0; o >>= 1) {
      dsq += __shfl_down(dsq, o);
      zsq += __shfl_down(zsq, o);
    }
    if (lane == 0) { red0[wid] = dsq; red1[wid] = zsq; }
    __syncthreads();
    if (tid == 0) {
      float sa = 0.f, sb = 0.f;
      for (int w2 = 0; w2 < 8; ++w2) { sa += red0[w2]; sb += red1[w2]; }
      bsums[((it & 1) << 8) + bid] = make_float2(sa, sb);
    }
    __threadfence();
    grid.sync();
    __threadfence();
    // every block recomputes the identical global decision (uniform break)
    float da = 0.f, db = 0.f;
    if (tid < 256) { float2 v = bsums[((it & 1) << 8) + tid]; da = v.x; db = v.y; }
#pragma unroll
    for (int o = 32; o > 0; o >>= 1) {
      da += __shfl_down(da, o);
      db += __shfl_down(db, o);
    }
    if (lane == 0) { red0[wid] = da; red1[wid] = db; }
    __syncthreads();
    if (tid == 0) {
      float sa = 0.f, sb = 0.f;
      for (int w2 = 0; w2 < 8; ++w2) { sa += red0[w2]; sb += red1[w2]; }
      sflag = (sqrtf(sa) < TOLF * (sqrtf(sb) + 1e-12f)) ? 1 : 0;
    }
    __syncthreads();
    if (sflag) break;
  }

  // final transposed write: out[n*NB + b] = y[b*NN + n]  (own tile only)
  for (int i = tid; i < 32 * 64; i += 512) {
    int bl = i & 31, nl = i >> 5;
    out[(size_t)(n0 + nl) * NB + b0 + bl] = y[(size_t)(b0 + bl) * NN + n0 + nl];
  }
}

extern "C" void kernel_launch(void* const* d_in, const int* in_sizes, int n_in,
                              void* d_out, int out_size, void* d_ws, size_t ws_size,
                              hipStream_t stream) {
  const float* A    = (const float*)d_in[0];
  const float* S    = (const float*)d_in[1];
  const float* mraw = (const float*)d_in[2];
  const float* U    = (const float*)d_in[3];
  const float* bias = (const float*)d_in[4];
  const float* x    = (const float*)d_in[5];
  float* out = (float*)d_out;

  char* base = (char*)d_ws;
  const size_t ASZ = (size_t)NN * KK * 2;  // 8 MiB per bf16 matrix
  u16* Aht = (u16*)(base);                 // dead after k_build_T
  u16* Alt = (u16*)(base + ASZ);           // dead after k_build_T
  u16* Thp = (u16*)(base + 2 * ASZ);
  u16* Tlp = (u16*)(base + 3 * ASZ);
  // alias the dead Aht/Alt region for iteration state:
  float*  cpp = (float*)(base + 0);
  float*  yp  = (float*)(base + 2097152);
  u16*    yhp = (u16*)(base + 4194304);
  u16*    ylp = (u16*)(base + 5242880);
  float2* bsp = (float2*)(base + 6291456);

  k_transpose_split<<<dim3(1024), dim3(256), 0, stream>>>(A, Aht, Alt);
  k_build_T<<<dim3(256), dim3(512), 0, stream>>>(Aht, Alt, S, mraw, Thp, Tlp);
  k_build_c<<<dim3(2048), dim3(256), 0, stream>>>(U, bias, x, cpp);

  void* kargs[] = { (void*)&Thp, (void*)&Tlp, (void*)&cpp, (void*)&yp,
                    (void*)&yhp, (void*)&ylp, (void*)&bsp, (void*)&out };
  hipLaunchCooperativeKernel((const void*)k_iterate, dim3(256), dim3(512),
                             kargs, 0, stream);
}

// Round 2
// 5023.310 us; speedup vs baseline: 2.4239x; 2.4239x over previous
//
#include <hip/hip_runtime.h>
#include <hip/hip_bf16.h>

typedef unsigned short u16;
typedef __attribute__((ext_vector_type(8))) short short8;
typedef __attribute__((ext_vector_type(4))) float f32x4;

static constexpr int NB = 256;    // batch
static constexpr int NN = 2048;   // hidden n
static constexpr int KK = 2048;   // contraction dim
static constexpr int DD = 512;    // input features
static constexpr float ALPHA = 0.1f;
static constexpr float TOLF = 1e-4f;
static constexpr int MAXIT = 300;

__device__ __forceinline__ float bf2f(u16 u) {
  union { unsigned int i; float f; } v; v.i = ((unsigned int)u) << 16; return v.f;
}
__device__ __forceinline__ u16 f2bf(float f) {  // RNE bf16
  union { float f; unsigned int i; } v; v.f = f;
  unsigned int x = v.i;
  return (u16)((x + 0x7fffu + ((x >> 16) & 1u)) >> 16);
}

// ---------------- K1: Aht[i][k] = bf16(A[k][i]), Alt = residual ----------------
__global__ __launch_bounds__(256) void k_transpose_split(
    const float* __restrict__ A, u16* __restrict__ Aht, u16* __restrict__ Alt) {
  __shared__ float tile[64][65];
  int bx = blockIdx.x & 31;   // i-tile
  int by = blockIdx.x >> 5;   // k-tile
  int i0 = bx << 6, k0 = by << 6;
  int c = threadIdx.x & 63, r4 = threadIdx.x >> 6;
  for (int rr = r4; rr < 64; rr += 4)
    tile[rr][c] = A[(size_t)(k0 + rr) * NN + i0 + c];
  __syncthreads();
  for (int rr = r4; rr < 64; rr += 4) {
    float v = tile[c][rr];                       // = A[k0+c][i0+rr]
    size_t o = (size_t)(i0 + rr) * KK + k0 + c;  // Aht[i][k]
    u16 hv = f2bf(v);
    Aht[o] = hv;
    Alt[o] = f2bf(v - bf2f(hv));
  }
}

// ------ K2: T = (1 - a*m) I + a*(S - S^T - A^T A), stored row-major bf16 split ------
__global__ __launch_bounds__(512) void k_build_T(
    const u16* __restrict__ Aht, const u16* __restrict__ Alt,
    const float* __restrict__ S, const float* __restrict__ mraw,
    u16* __restrict__ Th, u16* __restrict__ Tl) {
  int bid = blockIdx.x;            // 256 blocks, output tile 128x128
  int it0 = (bid >> 4) << 7;
  int jt0 = (bid & 15) << 7;
  int lane = threadIdx.x & 63, wid = threadIdx.x >> 6;
  int wm = wid >> 2, wn = wid & 3; // 2x4 waves, wave tile 64x32
  int ib = it0 + wm * 64;
  int jb = jt0 + wn * 32;
  int lcol = lane & 15, kg = lane >> 4;
  f32x4 acc[4][2] = {};
  size_t ar[4], br[2];
#pragma unroll
  for (int mf = 0; mf < 4; ++mf) ar[mf] = (size_t)(ib + mf * 16 + lcol) * KK + kg * 8;
#pragma unroll
  for (int nf = 0; nf < 2; ++nf) br[nf] = (size_t)(jb + nf * 16 + lcol) * KK + kg * 8;
  for (int kk = 0; kk < KK; kk += 32) {
    short8 ah[4], al[4], bh[2], bl[2];
#pragma unroll
    for (int mf = 0; mf < 4; ++mf) {
      ah[mf] = *(const short8*)(Aht + ar[mf] + kk);
      al[mf] = *(const short8*)(Alt + ar[mf] + kk);
    }
#pragma unroll
    for (int nf = 0; nf < 2; ++nf) {
      bh[nf] = *(const short8*)(Aht + br[nf] + kk);
      bl[nf] = *(const short8*)(Alt + br[nf] + kk);
    }
#pragma unroll
    for (int mf = 0; mf < 4; ++mf)
#pragma unroll
      for (int nf = 0; nf < 2; ++nf) {
        acc[mf][nf] = __builtin_amdgcn_mfma_f32_16x16x32_bf16(ah[mf], bh[nf], acc[mf][nf], 0, 0, 0);
        acc[mf][nf] = __builtin_amdgcn_mfma_f32_16x16x32_bf16(al[mf], bh[nf], acc[mf][nf], 0, 0, 0);
        acc[mf][nf] = __builtin_amdgcn_mfma_f32_16x16x32_bf16(ah[mf], bl[nf], acc[mf][nf], 0, 0, 0);
      }
  }
  float m = log1pf(expf(mraw[0]));   // softplus
  float dg = 1.0f - ALPHA * m;
#pragma unroll
  for (int mf = 0; mf < 4; ++mf)
#pragma unroll
    for (int nf = 0; nf < 2; ++nf)
#pragma unroll
      for (int e = 0; e < 4; ++e) {
        int i = ib + mf * 16 + kg * 4 + e;   // D row = (lane>>4)*4+e  [m89-verified]
        int j = jb + nf * 16 + lcol;         // D col = lane&15
        float tv = ALPHA * (S[(size_t)i * NN + j] - S[(size_t)j * NN + i] - acc[mf][nf][e]);
        if (i == j) tv += dg;
        size_t o = (size_t)i * KK + j;
        u16 hv = f2bf(tv);
        Th[o] = hv;
        Tl[o] = f2bf(tv - bf2f(hv));
      }
}

// ---------------- K3: cp[b][n] = a*(U[n,:]·x[b,:] + bias[n]) ----------------
__global__ __launch_bounds__(256) void k_build_c(
    const float* __restrict__ U, const float* __restrict__ bias,
    const float* __restrict__ x, float* __restrict__ cp) {
  int b = blockIdx.x >> 3;
  int n = ((blockIdx.x & 7) << 8) + threadIdx.x;
  const float4* xr = (const float4*)(x + (size_t)b * DD);
  const float4* ur = (const float4*)(U + (size_t)n * DD);
  float acc = 0.f;
  for (int d = 0; d < DD / 4; ++d) {
    float4 xv = xr[d], uv = ur[d];
    acc += xv.x * uv.x + xv.y * uv.y + xv.z * uv.z + xv.w * uv.w;
  }
  cp[(size_t)b * NN + n] = ALPHA * (acc + bias[n]);
}

// ---------------- K4: fixed-point iteration, hand-rolled light barrier ----------------
// z lives as bf16 split (yh/yl) in global + fp32 in registers (each thread owns the
// same 4 elements every iteration). One release+acquire fence pair per BLOCK per
// iteration (wave 0 only); global barrier = monotonic atomic counter + sleep-spin.
__global__ __launch_bounds__(512) void k_iterate(
    const u16* __restrict__ Th, const u16* __restrict__ Tl,
    const float* __restrict__ cp,
    u16* __restrict__ yh, u16* __restrict__ yl,
    float2* __restrict__ bsums, unsigned int* __restrict__ ctr,
    float* __restrict__ out) {
  int bid = blockIdx.x;
  // XCD swizzle: blocks with bid%8==x handle n-panels [256x, 256x+256) -> XCD-local T slice
  int xcd = bid & 7, g = bid >> 3;
  int ntile = xcd * 4 + (g & 3);   // 0..31
  int btile = g >> 2;              // 0..7
  int b0 = btile * 32, n0 = ntile * 64;
  int tid = threadIdx.x, lane = tid & 63, wid = tid >> 6;
  int wm = wid >> 2, wn = wid & 3;   // 2x4 waves of 16x16
  int lcol = lane & 15, kg = lane >> 4;
  int wb = b0 + wm * 16;
  int wn0 = n0 + wn * 16;
  const u16* pAh = yh + (size_t)(wb + lcol) * KK + kg * 8;
  const u16* pAl = yl + (size_t)(wb + lcol) * KK + kg * 8;
  const u16* pBh = Th + (size_t)(wn0 + lcol) * KK + kg * 8;
  const u16* pBl = Tl + (size_t)(wn0 + lcol) * KK + kg * 8;
  int eb = wb + kg * 4;   // 4 output batch rows owned by this thread
  int en = wn0 + lcol;    // output n column owned by this thread

  float zreg[4], creg[4];
#pragma unroll
  for (int e = 0; e < 4; ++e) {
    zreg[e] = 0.f;
    creg[e] = cp[(size_t)(eb + e) * NN + en];
  }

  __shared__ float red0[8], red1[8];
  __shared__ int sflag;

  for (int it = 0; it < MAXIT; ++it) {
    f32x4 a0 = {0.f, 0.f, 0.f, 0.f};
    f32x4 a1 = {0.f, 0.f, 0.f, 0.f};
    f32x4 a2 = {0.f, 0.f, 0.f, 0.f};
    if (it > 0) {
#pragma unroll 8
      for (int kk = 0; kk < KK; kk += 32) {
        short8 avh = *(const short8*)(pAh + kk);
        short8 avl = *(const short8*)(pAl + kk);
        short8 bvh = *(const short8*)(pBh + kk);
        short8 bvl = *(const short8*)(pBl + kk);
        a0 = __builtin_amdgcn_mfma_f32_16x16x32_bf16(avh, bvh, a0, 0, 0, 0);
        a1 = __builtin_amdgcn_mfma_f32_16x16x32_bf16(avl, bvh, a1, 0, 0, 0);
        a2 = __builtin_amdgcn_mfma_f32_16x16x32_bf16(avh, bvl, a2, 0, 0, 0);
      }
    }
    float dsq = 0.f, zsq = 0.f;
#pragma unroll
    for (int e = 0; e < 4; ++e) {
      size_t idx = (size_t)(eb + e) * NN + en;
      float p = a0[e] + a1[e] + a2[e] + creg[e];
      float zn = fmaxf(p, 0.f);
      float d = zn - zreg[e];
      dsq += d * d;
      zsq += zreg[e] * zreg[e];
      zreg[e] = zn;
      u16 hv = f2bf(zn);
      yh[idx] = hv;
      yl[idx] = f2bf(zn - bf2f(hv));
    }
#pragma unroll
    for (int o = 32; o > 0; o >>= 1) {
      dsq += __shfl_down(dsq, o);
      zsq += __shfl_down(zsq, o);
    }
    if (lane == 0) { red0[wid] = dsq; red1[wid] = zsq; }
    __syncthreads();   // also drains every wave's yh/yl stores to L2
    if (tid == 0) {
      float sa = 0.f, sb = 0.f;
      for (int w = 0; w < 8; ++w) { sa += red0[w]; sb += red1[w]; }
      bsums[((it & 1) << 8) + bid] = make_float2(sa, sb);
    }
    if (wid == 0) {
      // release: flush this XCD's dirty L2 lines (all waves' stores) to coherent point
      __builtin_amdgcn_fence(__ATOMIC_RELEASE, "agent");
      if (lane == 0) {
        __hip_atomic_fetch_add(ctr, 1u, __ATOMIC_RELAXED, __HIP_MEMORY_SCOPE_AGENT);
        unsigned tgt = (unsigned)(it + 1) * 256u;
        while (__hip_atomic_load(ctr, __ATOMIC_RELAXED, __HIP_MEMORY_SCOPE_AGENT) < tgt)
          __builtin_amdgcn_s_sleep(8);
      }
      // acquire: invalidate stale L2 lines before reading other blocks' z / bsums
      __builtin_amdgcn_fence(__ATOMIC_ACQUIRE, "agent");
      // grid-uniform convergence decision (identical data + order in every block)
      float da = 0.f, db = 0.f;
#pragma unroll
      for (int q = 0; q < 4; ++q) {
        float2 v = bsums[((it & 1) << 8) + lane + q * 64];
        da += v.x; db += v.y;
      }
#pragma unroll
      for (int o = 32; o > 0; o >>= 1) {
        da += __shfl_down(da, o);
        db += __shfl_down(db, o);
      }
      if (lane == 0) sflag = (sqrtf(da) < TOLF * (sqrtf(db) + 1e-12f)) ? 1 : 0;
    }
    __syncthreads();
    if (sflag) break;
  }

  // final write: out[n*NB + b], 4 consecutive b per thread -> one float4
  *(float4*)(out + (size_t)en * NB + eb) = make_float4(zreg[0], zreg[1], zreg[2], zreg[3]);
}

extern "C" void kernel_launch(void* const* d_in, const int* in_sizes, int n_in,
                              void* d_out, int out_size, void* d_ws, size_t ws_size,
                              hipStream_t stream) {
  const float* A    = (const float*)d_in[0];
  const float* S    = (const float*)d_in[1];
  const float* mraw = (const float*)d_in[2];
  const float* U    = (const float*)d_in[3];
  const float* bias = (const float*)d_in[4];
  const float* x    = (const float*)d_in[5];
  float* out = (float*)d_out;

  char* base = (char*)d_ws;
  const size_t ASZ = (size_t)NN * KK * 2;  // 8 MiB per bf16 matrix
  u16* Aht = (u16*)(base);                 // dead after k_build_T
  u16* Alt = (u16*)(base + ASZ);           // dead after k_build_T
  u16* Thp = (u16*)(base + 2 * ASZ);
  u16* Tlp = (u16*)(base + 3 * ASZ);
  // alias the dead Aht region for iteration state (written only after k_build_T ran):
  float*    cpp  = (float*)(base + 0);                       // 2 MiB
  u16*      yhp  = (u16*)(base + 2u * 1024 * 1024);          // 1 MiB
  u16*      ylp  = (u16*)(base + 3u * 1024 * 1024);          // 1 MiB
  float2*   bsp  = (float2*)(base + 4u * 1024 * 1024);       // 4 KiB
  unsigned* ctrp = (unsigned*)(base + 4u * 1024 * 1024 + 64 * 1024);

  hipMemsetAsync(ctrp, 0, sizeof(unsigned), stream);

  k_transpose_split<<<dim3(1024), dim3(256), 0, stream>>>(A, Aht, Alt);
  k_build_T<<<dim3(256), dim3(512), 0, stream>>>(Aht, Alt, S, mraw, Thp, Tlp);
  k_build_c<<<dim3(2048), dim3(256), 0, stream>>>(U, bias, x, cpp);

  void* kargs[] = { (void*)&Thp, (void*)&Tlp, (void*)&cpp,
                    (void*)&yhp, (void*)&ylp, (void*)&bsp, (void*)&ctrp, (void*)&out };
  hipLaunchCooperativeKernel((const void*)k_iterate, dim3(256), dim3(512),
                             kargs, 0, stream);
}